// Round 13
// baseline (125.536 us; speedup 1.0000x reference)
//
#include <hip/hip_runtime.h>
#include <math.h>

using short8  = __attribute__((ext_vector_type(8))) short;
using ushort8 = __attribute__((ext_vector_type(8))) unsigned short;
using f32x4   = __attribute__((ext_vector_type(4))) float;

constexpr int DIM = 1024, NB = 8, NH = 2, HD = 32;
constexpr int T   = 32;       // tokens per WG (2 sub-tiles of 16)
constexpr float SCALE = 0.17677669529663687f;  // HD^-0.5, folded into wq at prep
constexpr int SXW = 1032;     // x-tile row stride (ushorts)
constexpr int SQW = 1536;     // qkv row stride (ushorts)

__device__ __forceinline__ unsigned short f2bf(float f) {
  unsigned u = __float_as_uint(f);
  u += 0x7fff + ((u >> 16) & 1);  // RNE
  return (unsigned short)(u >> 16);
}
__device__ __forceinline__ float bf2f(unsigned short h) {
  return __uint_as_float((unsigned)h << 16);
}
__device__ __forceinline__ unsigned pack2bf(float lo, float hi) {
  return (unsigned)f2bf(lo) | ((unsigned)f2bf(hi) << 16);
}

// q/k region addressing with bank swizzle (proven rounds 9/11)
__device__ __forceinline__ int qk_off(int R, int blk, int sub) {
  return R * 32 + ((blk ^ (R & 3)) * 8) + sub;
}

// ---- prep: weights -> bf16 in MFMA fragment order (verified round 5/7) ----
__global__ __launch_bounds__(256) void prep_weights(
    const float* __restrict__ wq, const float* __restrict__ wk,
    const float* __restrict__ wv, const float* __restrict__ wf,
    unsigned short* __restrict__ ws)
{
  int gid = blockIdx.x * 256 + threadIdx.x;   // 0..262143
  if (gid < 196608) {
    int t = gid >> 11, r = gid & 2047;
    int s = r >> 9, l = (r >> 3) & 63, z = r & 7;
    int met = t >> 3, n = t & 7, m = met >> 2, et = met & 3;
    int fr = l & 15, fg = l >> 4;
    int e = et * 16 + fr, k = s * 32 + fg * 8 + z;
    const float* w = (m == 0) ? wq : (m == 1) ? wk : wv;
    float v = w[n * 8192 + k * 64 + e];
    if (m == 0) v *= SCALE;
    ws[gid] = f2bf(v);
  } else {
    int g2 = gid - 196608;
    int t = g2 >> 10, r = g2 & 1023;
    int s = r >> 9, l = (r >> 3) & 63, z = r & 7;
    int n = t >> 3, et = t & 7;
    int fr = l & 15, fg = l >> 4;
    int eo = et * 16 + fr, k = s * 32 + fg * 8 + z;
    ws[gid] = f2bf(wf[n * 8192 + k * 128 + eo]);
  }
}

// ---- fused kernel: 32 tokens/WG, 512 threads; each weight load feeds 2 sub-tiles ----
__global__ __launch_bounds__(512, 2) void gc_fused(
    const float* __restrict__ x,
    const unsigned short* __restrict__ wsw,   // 96 qkv tiles [2048 ush]
    const unsigned short* __restrict__ wsf,   // 64 wf tiles  [1024 ush]
    float* __restrict__ out)
{
  // overlays: stage-x rows at r*SXW (33024 ush); after barrier qkv rows t*SQW.
  // per token row: q/attn_out [0,512) swizzled qk_off | k [512,1024) swizzled |
  // vT planes [1024,1536): 1024 + kh*256 + dd*8 + (k&7).
  __shared__ __align__(16) unsigned short smem[T * SQW];    // 96 KB -> 1 WG/CU

  const int tid  = threadIdx.x;
  const int lane = tid & 63;
  const int w    = tid >> 6;
  const int fr   = lane & 15;
  const int fg   = lane >> 4;
  const long tok0 = (long)blockIdx.x * T;

  // ---- stage x -> bf16 LDS (coalesced; proven pattern, 8 chunks/thread) ----
  {
    const float* xb = x + tok0 * DIM;
    float4 xa[8], xc[8];
    #pragma unroll
    for (int jj = 0; jj < 8; ++jj) {
      int chunk = tid + 512 * jj;                  // 4096 chunks of 8 floats
      const float* src = xb + (long)(chunk >> 7) * DIM + (chunk & 127) * 8;
      xa[jj] = *reinterpret_cast<const float4*>(src);
      xc[jj] = *reinterpret_cast<const float4*>(src + 4);
    }
    #pragma unroll
    for (int jj = 0; jj < 8; ++jj) {
      int chunk = tid + 512 * jj;
      ushort8 v;
      v[0] = f2bf(xa[jj].x); v[1] = f2bf(xa[jj].y);
      v[2] = f2bf(xa[jj].z); v[3] = f2bf(xa[jj].w);
      v[4] = f2bf(xc[jj].x); v[5] = f2bf(xc[jj].y);
      v[6] = f2bf(xc[jj].z); v[7] = f2bf(xc[jj].w);
      *reinterpret_cast<ushort8*>(&smem[(chunk >> 7) * SXW + (chunk & 127) * 8]) = v;
    }
  }
  __syncthreads();

  // ---- phase A: 12 weight tiles/wave, each applied to BOTH 16-token sub-tiles ----
  ushort4 qreg[12][2];
  {
    short8 wfr[2][4];                              // dbuf prefetch (proven round 5/9)
    const unsigned short* wp0 = wsw + (w * 12) * 2048 + lane * 8;
    #pragma unroll
    for (int s = 0; s < 4; ++s)
      wfr[0][s] = *reinterpret_cast<const short8*>(wp0 + s * 512);
    #pragma unroll
    for (int j = 0; j < 12; ++j) {
      const int cc = w * 12 + j;
      const int n  = cc & 7;
      if (j < 11) {
        const unsigned short* wpn = wsw + (cc + 1) * 2048 + lane * 8;
        #pragma unroll
        for (int s = 0; s < 4; ++s)
          wfr[(j + 1) & 1][s] = *reinterpret_cast<const short8*>(wpn + s * 512);
      }
      short8 b0[4], b1[4];
      #pragma unroll
      for (int s = 0; s < 4; ++s) {
        b0[s] = *reinterpret_cast<const short8*>(&smem[fr * SXW + n * 128 + s * 32 + fg * 8]);
        b1[s] = *reinterpret_cast<const short8*>(&smem[(fr + 16) * SXW + n * 128 + s * 32 + fg * 8]);
      }
      f32x4 a0 = {0.f, 0.f, 0.f, 0.f}, a1 = {0.f, 0.f, 0.f, 0.f};
      #pragma unroll
      for (int s = 0; s < 4; ++s) {
        a0 = __builtin_amdgcn_mfma_f32_16x16x32_bf16(wfr[j & 1][s], b0[s], a0, 0, 0, 0);
        a1 = __builtin_amdgcn_mfma_f32_16x16x32_bf16(wfr[j & 1][s], b1[s], a1, 0, 0, 0);
      }
      qreg[j][0].x = f2bf(a0[0]); qreg[j][0].y = f2bf(a0[1]);
      qreg[j][0].z = f2bf(a0[2]); qreg[j][0].w = f2bf(a0[3]);
      qreg[j][1].x = f2bf(a1[0]); qreg[j][1].y = f2bf(a1[1]);
      qreg[j][1].z = f2bf(a1[2]); qreg[j][1].w = f2bf(a1[3]);
    }
  }
  __syncthreads();                                 // x region dies

  // ---- write qkv frags: q/k swizzled, vT as two k-half planes (proven round 11) ----
  {
    #pragma unroll
    for (int j = 0; j < 12; ++j) {
      const int cc = w * 12 + j;
      const int met = cc >> 3, n = cc & 7;
      const int m = met >> 2, e0 = (met & 3) * 16;
      #pragma unroll
      for (int u = 0; u < 2; ++u) {
        const int row = u * 16 + fr;
        if (m < 2) {
          const int e00 = e0 + fg * 4;
          const int h = e00 >> 5, dd0 = e00 & 31;
          const int R = 2 * n + h;
          *reinterpret_cast<ushort4*>(
              &smem[row * SQW + m * 512 + qk_off(R, dd0 >> 3, dd0 & 7)]) = qreg[j][u];
        } else {
          const unsigned short vals[4] = {qreg[j][u].x, qreg[j][u].y,
                                          qreg[j][u].z, qreg[j][u].w};
          #pragma unroll
          for (int r = 0; r < 4; ++r) {
            const int e = e0 + fg * 4 + r, dd = e & 31, h = e >> 5;
            smem[row * SQW + 1024 + h * 256 + dd * 8 + n] = vals[r];
          }
        }
      }
    }
  }
  __syncthreads();

  // ---- phase B': scores (MFMA) + softmax + PV (MFMA chain); proven round 9/11 ----
  // Wave w owns tokens t = w*4 + tt, tt = 0..3.
  {
    const int la = lane & 15, ga = lane >> 4;
    const int R  = 2 * (la & 7) + (la >> 3);
    const int qoff = qk_off(R, ga, 0);
    const bool useful = ((ga >> 1) == (la >> 3));
    const bool kvalid = (ga < 2);
    const int srcA = (ga * 32 + la) & 63;
    #pragma unroll
    for (int tt = 0; tt < 4; ++tt) {
      const int t = w * 4 + tt;
      const unsigned short* tb = &smem[t * SQW];
      short8 kfr = *reinterpret_cast<const short8*>(tb + 512 + qoff);
      short8 qfr = *reinterpret_cast<const short8*>(tb + qoff);
      f32x4 zero = {0.f, 0.f, 0.f, 0.f};
      f32x4 s = __builtin_amdgcn_mfma_f32_16x16x32_bf16(kfr, qfr, zero, 0, 0, 0);
      float m4 = fmaxf(fmaxf(s[0], s[1]), fmaxf(s[2], s[3]));
      float mx = fmaxf(m4, __shfl_xor(m4, 16));
      float e0 = __expf(s[0] - mx), e1 = __expf(s[1] - mx);
      float e2 = __expf(s[2] - mx), e3 = __expf(s[3] - mx);
      float sm  = e0 + e1 + e2 + e3;
      float smt = sm + __shfl_xor(sm, 16);
      float inv = useful ? (1.f / smt) : 0.f;      // smt >= 1 for useful lanes
      unsigned pk01 = pack2bf(e0 * inv, e1 * inv);
      unsigned pk23 = pack2bf(e2 * inv, e3 * inv);
      unsigned b0 = (unsigned)__builtin_amdgcn_ds_bpermute(srcA * 4, (int)pk01);
      unsigned b1 = (unsigned)__builtin_amdgcn_ds_bpermute(srcA * 4, (int)pk23);
      unsigned b2 = (unsigned)__builtin_amdgcn_ds_bpermute(((srcA + 16) & 63) * 4, (int)pk01);
      unsigned b3 = (unsigned)__builtin_amdgcn_ds_bpermute(((srcA + 16) & 63) * 4, (int)pk23);
      union { unsigned u[4]; short8 s8; } pb;
      pb.u[0] = kvalid ? b0 : 0u;  pb.u[1] = kvalid ? b1 : 0u;
      pb.u[2] = kvalid ? b2 : 0u;  pb.u[3] = kvalid ? b3 : 0u;
      #pragma unroll
      for (int dh = 0; dh < 2; ++dh) {
        short8 va = *reinterpret_cast<const short8*>(
            tb + 1024 + (ga & 1) * 256 + (dh * 16 + la) * 8);
        f32x4 o = __builtin_amdgcn_mfma_f32_16x16x32_bf16(va, pb.s8, zero, 0, 0, 0);
        ushort4 ou;
        ou.x = f2bf(o[0]); ou.y = f2bf(o[1]); ou.z = f2bf(o[2]); ou.w = f2bf(o[3]);
        const int blk = 2 * dh + (ga >> 1);
        *reinterpret_cast<ushort4*>(
            &smem[t * SQW + qk_off(R, blk, (ga & 1) * 4)]) = ou;
      }
    }
  }
  __syncthreads();

  // ---- phase D: out = attn_out @ wf; wave w owns n = w, both sub-tiles ----
  {
    const int n = w;
    short8 bfr[2][2];
    #pragma unroll
    for (int u = 0; u < 2; ++u)
      #pragma unroll
      for (int s = 0; s < 2; ++s) {
        const int R = 2 * n + s;                   // h = s, dd = fg*8 -> blk = fg
        bfr[u][s] = *reinterpret_cast<const short8*>(
            &smem[(u * 16 + fr) * SQW + qk_off(R, fg, 0)]);
      }
    #pragma unroll
    for (int et = 0; et < 8; ++et) {
      const unsigned short* wp = wsf + (n * 8 + et) * 1024 + lane * 8;
      short8 wfd0 = *reinterpret_cast<const short8*>(wp);
      short8 wfd1 = *reinterpret_cast<const short8*>(wp + 512);
      #pragma unroll
      for (int u = 0; u < 2; ++u) {
        f32x4 acc = {0.f, 0.f, 0.f, 0.f};
        acc = __builtin_amdgcn_mfma_f32_16x16x32_bf16(wfd0, bfr[u][0], acc, 0, 0, 0);
        acc = __builtin_amdgcn_mfma_f32_16x16x32_bf16(wfd1, bfr[u][1], acc, 0, 0, 0);
        float4 o; o.x = acc[0]; o.y = acc[1]; o.z = acc[2]; o.w = acc[3];
        *reinterpret_cast<float4*>(
            out + (tok0 + u * 16 + fr) * DIM + n * 128 + et * 16 + fg * 4) = o;
      }
    }
  }
}

extern "C" void kernel_launch(void* const* d_in, const int* in_sizes, int n_in,
                              void* d_out, int out_size, void* d_ws, size_t ws_size,
                              hipStream_t stream) {
  const float* x  = (const float*)d_in[0];
  const float* wq = (const float*)d_in[1];
  const float* wk = (const float*)d_in[2];
  const float* wv = (const float*)d_in[3];
  const float* wf = (const float*)d_in[4];
  float* out = (float*)d_out;
  unsigned short* ws = (unsigned short*)d_ws;

  prep_weights<<<dim3(1024), dim3(256), 0, stream>>>(wq, wk, wv, wf, ws);

  const int tokens = in_sizes[0] / DIM;   // 32768
  gc_fused<<<dim3(tokens / T), dim3(512), 0, stream>>>(x, ws, ws + 196608, out);
}

// Round 14
// 108.470 us; speedup vs baseline: 1.1573x; 1.1573x over previous
//
#include <hip/hip_runtime.h>
#include <math.h>

using short8  = __attribute__((ext_vector_type(8))) short;
using ushort8 = __attribute__((ext_vector_type(8))) unsigned short;
using f32x4   = __attribute__((ext_vector_type(4))) float;

constexpr int DIM = 1024, NB = 8, NH = 2, HD = 32;
constexpr float SCALE = 0.17677669529663687f;  // HD^-0.5, folded into wq at prep
constexpr int SQW = 1536;     // qkv row stride (ushorts)

__device__ __forceinline__ unsigned short f2bf(float f) {
  unsigned u = __float_as_uint(f);
  u += 0x7fff + ((u >> 16) & 1);  // RNE
  return (unsigned short)(u >> 16);
}
__device__ __forceinline__ float bf2f(unsigned short h) {
  return __uint_as_float((unsigned)h << 16);
}
__device__ __forceinline__ unsigned pack2bf(float lo, float hi) {
  return (unsigned)f2bf(lo) | ((unsigned)f2bf(hi) << 16);
}

// q/k region addressing with bank swizzle (proven rounds 9/11/13)
__device__ __forceinline__ int qk_off(int R, int blk, int sub) {
  return R * 32 + ((blk ^ (R & 3)) * 8) + sub;
}

// ---- prep: weights -> bf16 in MFMA fragment order (verified round 5/7) ----
__global__ __launch_bounds__(256) void prep_weights(
    const float* __restrict__ wq, const float* __restrict__ wk,
    const float* __restrict__ wv, const float* __restrict__ wf,
    unsigned short* __restrict__ ws)
{
  int gid = blockIdx.x * 256 + threadIdx.x;   // 0..262143
  if (gid < 196608) {
    int t = gid >> 11, r = gid & 2047;
    int s = r >> 9, l = (r >> 3) & 63, z = r & 7;
    int met = t >> 3, n = t & 7, m = met >> 2, et = met & 3;
    int fr = l & 15, fg = l >> 4;
    int e = et * 16 + fr, k = s * 32 + fg * 8 + z;
    const float* w = (m == 0) ? wq : (m == 1) ? wk : wv;
    float v = w[n * 8192 + k * 64 + e];
    if (m == 0) v *= SCALE;
    ws[gid] = f2bf(v);
  } else {
    int g2 = gid - 196608;
    int t = g2 >> 10, r = g2 & 1023;
    int s = r >> 9, l = (r >> 3) & 63, z = r & 7;
    int n = t >> 3, et = t & 7;
    int fr = l & 15, fg = l >> 4;
    int eo = et * 16 + fr, k = s * 32 + fg * 8 + z;
    ws[gid] = f2bf(wf[n * 8192 + k * 128 + eo]);
  }
}

// ---- fused: 16 tokens/WG, 512 threads; wave w owns block n = w end-to-end.
// x B-frags load DIRECTLY from global (no staging, no x-LDS); WG reads x once.
__global__ __launch_bounds__(512, 6) void gc_fused(
    const float* __restrict__ x,
    const unsigned short* __restrict__ wsw,   // 96 qkv tiles [2048 ush], id = met*8+n
    const unsigned short* __restrict__ wsf,   // 64 wf tiles  [1024 ush], id = n*8+et
    float* __restrict__ out)
{
  // qkv rows at t*SQW: q/attn_out [0,512) swizzled qk_off | k [512,1024) swizzled |
  // vT planes [1024,1536): 1024 + kh*256 + dd*8 + (k&7).
  __shared__ __align__(16) unsigned short smem[16 * SQW];   // 48 KB -> 3 WG/CU

  const int tid  = threadIdx.x;
  const int lane = tid & 63;
  const int w    = tid >> 6;
  const int fr   = lane & 15;
  const int fg   = lane >> 4;
  const int n    = w;                        // this wave's block column
  const long tok0 = (long)blockIdx.x * 16;

  // ---- x B-frags: 8 float4 direct global loads, convert in regs (16 bf16 regs) ----
  short8 bfr[4];
  {
    const float* xp = x + (tok0 + fr) * DIM + n * 128 + fg * 8;
    #pragma unroll
    for (int s = 0; s < 4; ++s) {
      float4 a = *reinterpret_cast<const float4*>(xp + s * 32);
      float4 c = *reinterpret_cast<const float4*>(xp + s * 32 + 4);
      short8 v;
      v[0] = (short)f2bf(a.x); v[1] = (short)f2bf(a.y);
      v[2] = (short)f2bf(a.z); v[3] = (short)f2bf(a.w);
      v[4] = (short)f2bf(c.x); v[5] = (short)f2bf(c.y);
      v[6] = (short)f2bf(c.z); v[7] = (short)f2bf(c.w);
      bfr[s] = v;
    }
  }

  // ---- phase A: 12 (m,et) tiles for n = w; dbuf weight prefetch; write qkv per tile ----
  {
    short8 wfr[2][4];
    const unsigned short* wp0 = wsw + (0 * 8 + n) * 2048 + lane * 8;
    #pragma unroll
    for (int s = 0; s < 4; ++s)
      wfr[0][s] = *reinterpret_cast<const short8*>(wp0 + s * 512);
    #pragma unroll
    for (int j = 0; j < 12; ++j) {           // j = met = m*4 + et
      if (j < 11) {
        const unsigned short* wpn = wsw + ((j + 1) * 8 + n) * 2048 + lane * 8;
        #pragma unroll
        for (int s = 0; s < 4; ++s)
          wfr[(j + 1) & 1][s] = *reinterpret_cast<const short8*>(wpn + s * 512);
      }
      f32x4 acc = {0.f, 0.f, 0.f, 0.f};
      #pragma unroll
      for (int s = 0; s < 4; ++s)
        acc = __builtin_amdgcn_mfma_f32_16x16x32_bf16(wfr[j & 1][s], bfr[s], acc, 0, 0, 0);
      const int m = j >> 2, e0 = (j & 3) * 16;
      // D: lane holds D[e = e0 + fg*4 + r][tok = fr]; write to this token's qkv row
      if (m < 2) {
        ushort4 d4;
        d4.x = f2bf(acc[0]); d4.y = f2bf(acc[1]);
        d4.z = f2bf(acc[2]); d4.w = f2bf(acc[3]);
        const int e00 = e0 + fg * 4;
        const int h = e00 >> 5, dd0 = e00 & 31;
        const int R = 2 * n + h;
        *reinterpret_cast<ushort4*>(
            &smem[fr * SQW + m * 512 + qk_off(R, dd0 >> 3, dd0 & 7)]) = d4;
      } else {
        #pragma unroll
        for (int r = 0; r < 4; ++r) {
          const int e = e0 + fg * 4 + r, dd = e & 31, h = e >> 5;
          smem[fr * SQW + 1024 + h * 256 + dd * 8 + n] = f2bf(acc[r]);
        }
      }
    }
  }
  __syncthreads();                           // all waves' qkv visible

  // ---- phase B': scores (MFMA) + softmax + PV (MFMA chain); proven 9/11/13 ----
  {
    const int la = lane & 15, ga = lane >> 4;
    const int R  = 2 * (la & 7) + (la >> 3);
    const int qoff = qk_off(R, ga, 0);
    const bool useful = ((ga >> 1) == (la >> 3));
    const bool kvalid = (ga < 2);
    const int srcA = (ga * 32 + la) & 63;
    #pragma unroll
    for (int tt = 0; tt < 2; ++tt) {
      const int t = w * 2 + tt;
      const unsigned short* tb = &smem[t * SQW];
      short8 kfr = *reinterpret_cast<const short8*>(tb + 512 + qoff);
      short8 qfr = *reinterpret_cast<const short8*>(tb + qoff);
      f32x4 zero = {0.f, 0.f, 0.f, 0.f};
      f32x4 s = __builtin_amdgcn_mfma_f32_16x16x32_bf16(kfr, qfr, zero, 0, 0, 0);
      float m4 = fmaxf(fmaxf(s[0], s[1]), fmaxf(s[2], s[3]));
      float mx = fmaxf(m4, __shfl_xor(m4, 16));
      float e0 = __expf(s[0] - mx), e1 = __expf(s[1] - mx);
      float e2 = __expf(s[2] - mx), e3 = __expf(s[3] - mx);
      float sm  = e0 + e1 + e2 + e3;
      float smt = sm + __shfl_xor(sm, 16);
      float inv = useful ? (1.f / smt) : 0.f;
      unsigned pk01 = pack2bf(e0 * inv, e1 * inv);
      unsigned pk23 = pack2bf(e2 * inv, e3 * inv);
      unsigned b0 = (unsigned)__builtin_amdgcn_ds_bpermute(srcA * 4, (int)pk01);
      unsigned b1 = (unsigned)__builtin_amdgcn_ds_bpermute(srcA * 4, (int)pk23);
      unsigned b2 = (unsigned)__builtin_amdgcn_ds_bpermute(((srcA + 16) & 63) * 4, (int)pk01);
      unsigned b3 = (unsigned)__builtin_amdgcn_ds_bpermute(((srcA + 16) & 63) * 4, (int)pk23);
      union { unsigned u[4]; short8 s8; } pb;
      pb.u[0] = kvalid ? b0 : 0u;  pb.u[1] = kvalid ? b1 : 0u;
      pb.u[2] = kvalid ? b2 : 0u;  pb.u[3] = kvalid ? b3 : 0u;
      #pragma unroll
      for (int dh = 0; dh < 2; ++dh) {
        short8 va = *reinterpret_cast<const short8*>(
            tb + 1024 + (ga & 1) * 256 + (dh * 16 + la) * 8);
        f32x4 o = __builtin_amdgcn_mfma_f32_16x16x32_bf16(va, pb.s8, zero, 0, 0, 0);
        ushort4 ou;
        ou.x = f2bf(o[0]); ou.y = f2bf(o[1]); ou.z = f2bf(o[2]); ou.w = f2bf(o[3]);
        const int blk = 2 * dh + (ga >> 1);
        *reinterpret_cast<ushort4*>(
            &smem[t * SQW + qk_off(R, blk, (ga & 1) * 4)]) = ou;
      }
    }
  }
  __syncthreads();

  // ---- phase D: out = attn_out @ wf; wave w owns n = w (proven round 9/11) ----
  {
    short8 bfr2[2];
    #pragma unroll
    for (int s = 0; s < 2; ++s) {
      const int R = 2 * n + s;               // h = s, dd = fg*8 -> blk = fg
      bfr2[s] = *reinterpret_cast<const short8*>(&smem[fr * SQW + qk_off(R, fg, 0)]);
    }
    #pragma unroll
    for (int et = 0; et < 8; ++et) {
      const unsigned short* wp = wsf + (n * 8 + et) * 1024 + lane * 8;
      short8 wfd0 = *reinterpret_cast<const short8*>(wp);
      short8 wfd1 = *reinterpret_cast<const short8*>(wp + 512);
      f32x4 acc = {0.f, 0.f, 0.f, 0.f};
      acc = __builtin_amdgcn_mfma_f32_16x16x32_bf16(wfd0, bfr2[0], acc, 0, 0, 0);
      acc = __builtin_amdgcn_mfma_f32_16x16x32_bf16(wfd1, bfr2[1], acc, 0, 0, 0);
      float4 o; o.x = acc[0]; o.y = acc[1]; o.z = acc[2]; o.w = acc[3];
      *reinterpret_cast<float4*>(out + (tok0 + fr) * DIM + n * 128 + et * 16 + fg * 4) = o;
    }
  }
}

extern "C" void kernel_launch(void* const* d_in, const int* in_sizes, int n_in,
                              void* d_out, int out_size, void* d_ws, size_t ws_size,
                              hipStream_t stream) {
  const float* x  = (const float*)d_in[0];
  const float* wq = (const float*)d_in[1];
  const float* wk = (const float*)d_in[2];
  const float* wv = (const float*)d_in[3];
  const float* wf = (const float*)d_in[4];
  float* out = (float*)d_out;
  unsigned short* ws = (unsigned short*)d_ws;

  prep_weights<<<dim3(1024), dim3(256), 0, stream>>>(wq, wk, wv, wf, ws);

  const int tokens = in_sizes[0] / DIM;   // 32768
  gc_fused<<<dim3(tokens / 16), dim3(512), 0, stream>>>(x, ws, ws + 196608, out);
}